// Round 10
// baseline (209.640 us; speedup 1.0000x reference)
//
#include <hip/hip_runtime.h>
#include <hip/hip_bf16.h>

#define B_  2
#define S_  2048
#define H_  1024
#define NH_ 16
#define HD_ 64
#define T_  (B_*S_)     // 4096 tokens
#define H3_ (3*H_)      // 3072

typedef float  floatx4 __attribute__((ext_vector_type(4)));
typedef __bf16 bf16x8  __attribute__((ext_vector_type(8)));

__device__ inline unsigned short f2bf_rn(float f) {
    union { float f; unsigned int u; } v; v.f = f;
    unsigned int u = v.u;
    u += 0x7fffu + ((u >> 16) & 1u);
    return (unsigned short)(u >> 16);
}
__device__ inline unsigned short f2bf_tr(float f) {   // truncate — self-consistent w/ MFMA-summed l
    union { float f; unsigned int u; } v; v.f = f;
    return (unsigned short)(v.u >> 16);
}
__device__ inline floatx4 fzero4() { floatx4 v; v[0]=0.f; v[1]=0.f; v[2]=0.f; v[3]=0.f; return v; }

// async global->LDS, 16B per lane; LDS dest = wave-uniform base + lane*16
__device__ inline void gload_lds16(const unsigned short* g, unsigned short* l) {
    __builtin_amdgcn_global_load_lds((const __attribute__((address_space(1))) unsigned int*)g,
                                     (__attribute__((address_space(3))) unsigned int*)l,
                                     16, 0, 0);
}

// ---------------------------------------------------------------- prep: weight cast+transpose AND layernorm, one launch
// grid: [0,4096) = LN token blocks; [4096, 4096+1088) = transpose tiles (768 qkvw + 320... 1024 ow/64² = 256 -> 1024 total)
#define TLD 72
__global__ __launch_bounds__(256) void prep_k(const float* __restrict__ x,
                                              const float* __restrict__ nw,
                                              const float* __restrict__ nb,
                                              unsigned short* __restrict__ xn,
                                              const float* __restrict__ qkvw,
                                              const float* __restrict__ ow,
                                              unsigned short* __restrict__ qkvwT,
                                              unsigned short* __restrict__ owT) {
    const int tid = threadIdx.x;
    if (blockIdx.x < T_) {
        // ---- LayerNorm (fp32 stats, bf16 out)
        const int t = blockIdx.x;
        const float4 v = reinterpret_cast<const float4*>(x + (size_t)t * H_)[tid];
        float s  = v.x + v.y + v.z + v.w;
        float s2 = v.x*v.x + v.y*v.y + v.z*v.z + v.w*v.w;
        for (int off = 32; off > 0; off >>= 1) {
            s  += __shfl_down(s,  off, 64);
            s2 += __shfl_down(s2, off, 64);
        }
        __shared__ float red[8];
        const int wave = tid >> 6, lane = tid & 63;
        if (lane == 0) { red[wave] = s; red[4 + wave] = s2; }
        __syncthreads();
        if (tid == 0) {
            red[0] = red[0] + red[1] + red[2] + red[3];
            red[4] = red[4] + red[5] + red[6] + red[7];
        }
        __syncthreads();
        const float mean = red[0] * (1.f / H_);
        const float var  = red[4] * (1.f / H_) - mean * mean;
        const float rstd = rsqrtf(var + 1e-5f);
        const float4 wv = reinterpret_cast<const float4*>(nw)[tid];
        const float4 bv = reinterpret_cast<const float4*>(nb)[tid];
        ushort4 o = make_ushort4(f2bf_rn((v.x - mean) * rstd * wv.x + bv.x),
                                 f2bf_rn((v.y - mean) * rstd * wv.y + bv.y),
                                 f2bf_rn((v.z - mean) * rstd * wv.z + bv.z),
                                 f2bf_rn((v.w - mean) * rstd * wv.w + bv.w));
        reinterpret_cast<ushort4*>(xn + (size_t)t * H_)[tid] = o;
    } else {
        // ---- cast + transpose 64x64 tile
        __shared__ unsigned short Ts[64 * TLD];
        int id = blockIdx.x - T_;
        const float* W; unsigned short* Wt; int N, nbase, kb;
        if (id < 768) { W = qkvw; Wt = qkvwT; N = H3_; nbase = (id % 48) * 64; kb = (id / 48) * 64; }
        else { id -= 768; W = ow; Wt = owT; N = H_; nbase = (id % 16) * 64; kb = (id / 16) * 64; }
        const int K = H_;
        #pragma unroll
        for (int p = 0; p < 4; p++) {
            const int krow = kb + p * 16 + (tid >> 4);
            const int ncol = (tid & 15) * 4;
            const float4 w = *reinterpret_cast<const float4*>(&W[(size_t)krow * N + nbase + ncol]);
            Ts[(ncol + 0) * TLD + p * 16 + (tid >> 4)] = f2bf_rn(w.x);
            Ts[(ncol + 1) * TLD + p * 16 + (tid >> 4)] = f2bf_rn(w.y);
            Ts[(ncol + 2) * TLD + p * 16 + (tid >> 4)] = f2bf_rn(w.z);
            Ts[(ncol + 3) * TLD + p * 16 + (tid >> 4)] = f2bf_rn(w.w);
        }
        __syncthreads();
        #pragma unroll
        for (int p = 0; p < 2; p++) {
            const int n = (tid >> 3) + p * 32;
            const int k8 = (tid & 7) * 8;
            const uint4 v = *reinterpret_cast<const uint4*>(&Ts[n * TLD + k8]);
            *reinterpret_cast<uint4*>(&Wt[(size_t)(nbase + n) * K + kb + k8]) = v;
        }
    }
}

// ---------------------------------------------------------------- shared GEMM core: BK=64 as two BK=32 sub-buffers
#define BM 128
#define BN 128

__device__ inline void gemm_core(const unsigned short* __restrict__ A,
                                 const unsigned short* __restrict__ Bt,
                                 int K, int mBase, int nBase,
                                 int tid, floatx4 acc[4][4],
                                 unsigned short* As0, unsigned short* As1,
                                 unsigned short* Bs0, unsigned short* Bs1) {
    const int lane = tid & 63;
    const int wave = tid >> 6;
    const int wr = wave >> 1, wc = wave & 1;
    const int srow = lane >> 2;        // 0..15
    const int scol = (lane & 3) * 8;   // 0,8,16,24
    const int mrow = lane & 15;
    const int koff = (lane >> 4) * 8;

    for (int kb = 0; kb < K; kb += 64) {
        __syncthreads();
        #pragma unroll
        for (int p = 0; p < 2; p++) {
            const int r = wave * 16 + p * 64;
            const size_t ga = (size_t)(mBase + r + srow) * K + kb + scol;
            const size_t gb = (size_t)(nBase + r + srow) * K + kb + scol;
            gload_lds16(&A [ga],      &As0[r * 32]);
            gload_lds16(&A [ga + 32], &As1[r * 32]);
            gload_lds16(&Bt[gb],      &Bs0[r * 32]);
            gload_lds16(&Bt[gb + 32], &Bs1[r * 32]);
        }
        __syncthreads();

        #pragma unroll
        for (int half = 0; half < 2; half++) {
            const unsigned short* As = half ? As1 : As0;
            const unsigned short* Bs = half ? Bs1 : Bs0;
            bf16x8 afrag[4], bfrag[4];
            #pragma unroll
            for (int mt = 0; mt < 4; mt++)
                afrag[mt] = *reinterpret_cast<const bf16x8*>(&As[(wr * 64 + mt * 16 + mrow) * 32 + koff]);
            #pragma unroll
            for (int nt = 0; nt < 4; nt++)
                bfrag[nt] = *reinterpret_cast<const bf16x8*>(&Bs[(wc * 64 + nt * 16 + mrow) * 32 + koff]);
            #pragma unroll
            for (int mt = 0; mt < 4; mt++)
                #pragma unroll
                for (int nt = 0; nt < 4; nt++)
                    acc[mt][nt] = __builtin_amdgcn_mfma_f32_16x16x32_bf16(afrag[mt], bfrag[nt], acc[mt][nt], 0, 0, 0);
        }
    }
}

// ---------------------------------------------------------------- QKV GEMM with fused bias+rotary+V-transpose epilogue
__global__ __launch_bounds__(256) void gemm_qkv_k(const unsigned short* __restrict__ A,
                                                  const unsigned short* __restrict__ Bt,
                                                  const float* __restrict__ bias,
                                                  unsigned short* __restrict__ Qo,
                                                  unsigned short* __restrict__ Ko,
                                                  unsigned short* __restrict__ Vto) {
    __shared__ unsigned short As0[BM * 32], As1[BM * 32];
    __shared__ unsigned short Bs0[BN * 32], Bs1[BN * 32];

    const int tid  = threadIdx.x;
    const int lane = tid & 63;
    const int wave = tid >> 6;
    const int wr = wave >> 1, wc = wave & 1;
    const int mBase = blockIdx.y * BM;
    const int nBase = blockIdx.x * BN;

    floatx4 acc[4][4];
    #pragma unroll
    for (int i = 0; i < 4; i++)
        #pragma unroll
        for (int j = 0; j < 4; j++) acc[i][j] = fzero4();

    gemm_core(A, Bt, H_, mBase, nBase, tid, acc, As0, As1, Bs0, Bs1);

    const int col0 = lane & 15;
    const int r0   = (lane >> 4) * 4;
    const int hg   = (nBase + wc * 64) >> 6;   // global head index (wave-uniform)
    const int sec  = hg >> 4;                  // 0=q 1=k 2=v
    const int h    = hg & 15;

    float bs[4];
    #pragma unroll
    for (int nt = 0; nt < 4; nt++) bs[nt] = bias[nBase + wc * 64 + nt * 16 + col0];

    if (sec < 2) {
        unsigned short* dst = (sec == 0) ? Qo : Ko;
        const float if0 = __expf((float)col0        * (-0.2878231366f));   // j = col0
        const float if1 = __expf((float)(16 + col0) * (-0.2878231366f));   // j = 16+col0
        #pragma unroll
        for (int mt = 0; mt < 4; mt++) {
            #pragma unroll
            for (int reg = 0; reg < 4; reg++) {
                const int t  = mBase + wr * 64 + mt * 16 + r0 + reg;
                const int bb = t >> 11;
                const int s  = t & (S_ - 1);
                float sn0, cs0, sn1, cs1;
                __sincosf((float)s * if0, &sn0, &cs0);
                __sincosf((float)s * if1, &sn1, &cs1);
                const float v0 = acc[mt][0][reg] + bs[0];   // d = col0
                const float v1 = acc[mt][1][reg] + bs[1];   // d = 16+col0
                const float v2 = acc[mt][2][reg] + bs[2];   // d = 32+col0
                const float v3 = acc[mt][3][reg] + bs[3];   // d = 48+col0
                const float o0 = v0 * cs0 - v2 * sn0;
                const float o1 = v1 * cs1 - v3 * sn1;
                const float o2 = v2 * cs0 + v0 * sn0;
                const float o3 = v3 * cs1 + v1 * sn1;
                const size_t rb = ((size_t)(bb * NH_ + h) * S_ + s) * HD_;
                dst[rb +      col0] = f2bf_rn(o0);
                dst[rb + 16 + col0] = f2bf_rn(o1);
                dst[rb + 32 + col0] = f2bf_rn(o2);
                dst[rb + 48 + col0] = f2bf_rn(o3);
            }
        }
    } else {
        #pragma unroll
        for (int mt = 0; mt < 4; mt++) {
            const int t0 = mBase + wr * 64 + mt * 16 + r0;   // 4 consecutive tokens, 4-aligned
            const int bb = t0 >> 11;
            const int s0 = t0 & (S_ - 1);
            #pragma unroll
            for (int nt = 0; nt < 4; nt++) {
                const int d = nt * 16 + col0;
                ushort4 o;
                o.x = f2bf_rn(acc[mt][nt][0] + bs[nt]);
                o.y = f2bf_rn(acc[mt][nt][1] + bs[nt]);
                o.z = f2bf_rn(acc[mt][nt][2] + bs[nt]);
                o.w = f2bf_rn(acc[mt][nt][3] + bs[nt]);
                *reinterpret_cast<ushort4*>(&Vto[((size_t)(bb * NH_ + h) * HD_ + d) * S_ + s0]) = o;
            }
        }
    }
}

// ---------------------------------------------------------------- proj GEMM: C = A @ Bt^T + bias (f32 out)
__global__ __launch_bounds__(256) void gemm_proj_k(const unsigned short* __restrict__ A,
                                                   const unsigned short* __restrict__ Bt,
                                                   const float* __restrict__ bias,
                                                   float* __restrict__ Cf,
                                                   int M, int N, int K) {
    __shared__ unsigned short As0[BM * 32], As1[BM * 32];
    __shared__ unsigned short Bs0[BN * 32], Bs1[BN * 32];

    const int tid  = threadIdx.x;
    const int lane = tid & 63;
    const int wave = tid >> 6;
    const int wr = wave >> 1, wc = wave & 1;
    const int mBase = blockIdx.y * BM;
    const int nBase = blockIdx.x * BN;

    floatx4 acc[4][4];
    #pragma unroll
    for (int i = 0; i < 4; i++)
        #pragma unroll
        for (int j = 0; j < 4; j++) acc[i][j] = fzero4();

    gemm_core(A, Bt, K, mBase, nBase, tid, acc, As0, As1, Bs0, Bs1);

    const int col0 = lane & 15;
    const int r0   = (lane >> 4) * 4;
    #pragma unroll
    for (int mt = 0; mt < 4; mt++) {
        #pragma unroll
        for (int nt = 0; nt < 4; nt++) {
            const int gcol = nBase + wc * 64 + nt * 16 + col0;
            const float bsv = bias[gcol];
            #pragma unroll
            for (int reg = 0; reg < 4; reg++) {
                const int grow = mBase + wr * 64 + mt * 16 + r0 + reg;
                Cf[(size_t)grow * N + gcol] = acc[mt][nt][reg] + bsv;
            }
        }
    }
}

// ---------------------------------------------------------------- flash attention: 128-key macro-tiles, balanced 768-block grid
// slot s<8: band 31-s (25..32 tiles); s in [8,16): bands (s-8, 23-s) = 17 tiles; s in [16,24): band s (17..24 tiles).
// CU receives slots {s, s+8, s+16} (ids = r mod 256 share a CU) -> exactly 66 tiles per CU, one resident round.
#define ALD 72
#define SCL2 0.1803368801f      /* 0.125 * log2(e) */
#define MNEG -14427.0f          /* -10000 * log2(e), causal fill */

__global__ __launch_bounds__(256, 3) void attn_k(const unsigned short* __restrict__ Q,
                                                 const unsigned short* __restrict__ Kg,
                                                 const unsigned short* __restrict__ Vt,
                                                 const int* __restrict__ mask,
                                                 unsigned short* __restrict__ ctx) {
    const int id   = blockIdx.x;            // 0..767
    const int bh   = id & 31;               // head pinned to XCD (id%8)
    const int slot = id >> 5;               // 0..23
    const int b    = bh >> 4;
    const int h    = bh & 15;
    const int tid  = threadIdx.x;
    const int lane = tid & 63;
    const int wave = tid >> 6;

    int v0, v1, nbands;
    if (slot < 8)       { v0 = 31 - slot; v1 = 0;         nbands = 1; }
    else if (slot < 16) { v0 = slot - 8;  v1 = 23 - slot; nbands = 2; }
    else                { v0 = slot;      v1 = 0;         nbands = 1; }

    __shared__ unsigned short Ks [2][64 * ALD];   // 18.4 KB
    __shared__ unsigned short Vts[2][64 * ALD];   // 18.4 KB
    __shared__ unsigned short Ps[4][16 * ALD];    //  9.2 KB -> 45 KB total

    const size_t base = (size_t)bh * S_ * HD_;
    const int mrow = lane & 15;
    const int koff = (lane >> 4) * 8;
    const int r0   = (lane >> 4) * 4;
    const int col0 = lane & 15;
    const int srow = tid >> 3;          // 0..31
    const int scol = (tid & 7) * 8;

    bf16x8 onesf;
    {
        const __bf16 ov = (__bf16)((mrow == 0) ? 1.f : 0.f);
        #pragma unroll
        for (int q = 0; q < 8; q++) onesf[q] = ov;
    }

    unsigned short* pw = Ps[wave];

    for (int bi = 0; bi < 2; bi++) {
        if (bi >= nbands) break;
        const int v = bi ? v1 : v0;
        const int qbase = v * 64 + wave * 16;
        if (bi) __syncthreads();            // band A's last LDS reads done before band B stages

        bf16x8 qf0 = *reinterpret_cast<const bf16x8*>(&Q[base + (size_t)(qbase + mrow) * HD_ + koff]);
        bf16x8 qf1 = *reinterpret_cast<const bf16x8*>(&Q[base + (size_t)(qbase + mrow) * HD_ + 32 + koff]);

        floatx4 Oacc[4];
        floatx4 Lacc = fzero4();
        #pragma unroll
        for (int nt = 0; nt < 4; nt++) Oacc[nt] = fzero4();

        // named prefetch registers (no runtime-indexed arrays -> no scratch)
        uint4 k00, k01, k10, k11, va00, va01, va10, va11;
        float mb00, mb01, mb02, mb03, mb10, mb11, mb12, mb13;
#define PF_TILE(TT, KR0, KR1, VR0, VR1, M0, M1, M2, M3) do {                                   \
        const int kb_ = (TT) * 64;                                                             \
        KR0 = *reinterpret_cast<const uint4*>(&Kg[base + (size_t)(kb_ + srow)      * HD_ + scol]); \
        KR1 = *reinterpret_cast<const uint4*>(&Kg[base + (size_t)(kb_ + srow + 32) * HD_ + scol]); \
        VR0 = *reinterpret_cast<const uint4*>(&Vt[base + (size_t)srow        * S_ + kb_ + scol]);  \
        VR1 = *reinterpret_cast<const uint4*>(&Vt[base + (size_t)(srow + 32) * S_ + kb_ + scol]);  \
        M0 = (1.f - (float)mask[b * S_ + kb_ +  0 + col0]) * MNEG;                             \
        M1 = (1.f - (float)mask[b * S_ + kb_ + 16 + col0]) * MNEG;                             \
        M2 = (1.f - (float)mask[b * S_ + kb_ + 32 + col0]) * MNEG;                             \
        M3 = (1.f - (float)mask[b * S_ + kb_ + 48 + col0]) * MNEG;                             \
    } while (0)
#define PREFETCH_MACRO(MI) do {                                                                \
        const int t0_ = min(2 * (MI), v);                                                      \
        const int t1_ = min(2 * (MI) + 1, v);                                                  \
        PF_TILE(t0_, k00, k01, va00, va01, mb00, mb01, mb02, mb03);                            \
        PF_TILE(t1_, k10, k11, va10, va11, mb10, mb11, mb12, mb13);                            \
    } while (0)

        const int nmac = (v + 2) >> 1;
        PREFETCH_MACRO(0);

        for (int mi = 0; mi < nmac; mi++) {
            if (mi) __syncthreads();                   // WAR: prior macro's LDS reads done
            *reinterpret_cast<uint4*>(&Ks [0][ srow       * ALD + scol]) = k00;
            *reinterpret_cast<uint4*>(&Ks [0][(srow + 32) * ALD + scol]) = k01;
            *reinterpret_cast<uint4*>(&Ks [1][ srow       * ALD + scol]) = k10;
            *reinterpret_cast<uint4*>(&Ks [1][(srow + 32) * ALD + scol]) = k11;
            *reinterpret_cast<uint4*>(&Vts[0][ srow       * ALD + scol]) = va00;
            *reinterpret_cast<uint4*>(&Vts[0][(srow + 32) * ALD + scol]) = va01;
            *reinterpret_cast<uint4*>(&Vts[1][ srow       * ALD + scol]) = va10;
            *reinterpret_cast<uint4*>(&Vts[1][(srow + 32) * ALD + scol]) = va11;
            __syncthreads();                           // staged tiles visible
            const float mc00 = mb00, mc01 = mb01, mc02 = mb02, mc03 = mb03;
            const float mc10 = mb10, mc11 = mb11, mc12 = mb12, mc13 = mb13;
            if (mi + 1 < nmac) PREFETCH_MACRO(mi + 1);

            #pragma unroll
            for (int half = 0; half < 2; half++) {
                const int kt = 2 * mi + half;
                if (half && kt > v) continue;          // wave-uniform skip (odd tile count)
                const int kb = kt * 64;
                const unsigned short* ks = Ks [half];
                const unsigned short* vs = Vts[half];
                const float c0 = half ? mc10 : mc00;
                const float c1 = half ? mc11 : mc01;
                const float c2 = half ? mc12 : mc02;
                const float c3 = half ? mc13 : mc03;

                floatx4 sc[4];
                #pragma unroll
                for (int nt = 0; nt < 4; nt++) {
                    const bf16x8 kf0 = *reinterpret_cast<const bf16x8*>(&ks[(nt * 16 + mrow) * ALD + koff]);
                    const bf16x8 kf1 = *reinterpret_cast<const bf16x8*>(&ks[(nt * 16 + mrow) * ALD + 32 + koff]);
                    floatx4 c = fzero4();
                    c = __builtin_amdgcn_mfma_f32_16x16x32_bf16(qf0, kf0, c, 0, 0, 0);
                    c = __builtin_amdgcn_mfma_f32_16x16x32_bf16(qf1, kf1, c, 0, 0, 0);
                    sc[nt] = c;
                }
                #pragma unroll
                for (int nt = 0; nt < 4; nt++) {
                    const float mbv = (nt == 0) ? c0 : (nt == 1) ? c1 : (nt == 2) ? c2 : c3;
                    #pragma unroll
                    for (int reg = 0; reg < 4; reg++)
                        sc[nt][reg] = sc[nt][reg] * SCL2 + mbv;
                }
                if (kt == v) {                          // causal: diagonal tile only
                    #pragma unroll
                    for (int nt = 0; nt < 4; nt++) {
                        const int key = kb + nt * 16 + col0;
                        #pragma unroll
                        for (int reg = 0; reg < 4; reg++)
                            if (key > qbase + r0 + reg) sc[nt][reg] = MNEG;
                    }
                }
                #pragma unroll
                for (int nt = 0; nt < 4; nt++)
                    #pragma unroll
                    for (int reg = 0; reg < 4; reg++)
                        pw[(r0 + reg) * ALD + nt * 16 + col0] = f2bf_tr(exp2f(sc[nt][reg]));
                const bf16x8 p0 = *reinterpret_cast<const bf16x8*>(&pw[mrow * ALD + koff]);
                const bf16x8 p1 = *reinterpret_cast<const bf16x8*>(&pw[mrow * ALD + 32 + koff]);
                #pragma unroll
                for (int nt = 0; nt < 4; nt++) {
                    const bf16x8 vf0 = *reinterpret_cast<const bf16x8*>(&vs[(nt * 16 + mrow) * ALD + koff]);
                    const bf16x8 vf1 = *reinterpret_cast<const bf16x8*>(&vs[(nt * 16 + mrow) * ALD + 32 + koff]);
                    Oacc[nt] = __builtin_amdgcn_mfma_f32_16x16x32_bf16(p0, vf0, Oacc[nt], 0, 0, 0);
                    Oacc[nt] = __builtin_amdgcn_mfma_f32_16x16x32_bf16(p1, vf1, Oacc[nt], 0, 0, 0);
                }
                Lacc = __builtin_amdgcn_mfma_f32_16x16x32_bf16(p0, onesf, Lacc, 0, 0, 0);
                Lacc = __builtin_amdgcn_mfma_f32_16x16x32_bf16(p1, onesf, Lacc, 0, 0, 0);
            }
        }
#undef PREFETCH_MACRO
#undef PF_TILE

        float rl[4];
        #pragma unroll
        for (int reg = 0; reg < 4; reg++) {
            const float lsum = __shfl(Lacc[reg], lane & 48, 64);
            rl[reg] = 1.f / lsum;
        }
        #pragma unroll
        for (int nt = 0; nt < 4; nt++)
            #pragma unroll
            for (int reg = 0; reg < 4; reg++) {
                const int q = qbase + r0 + reg;
                const int d = nt * 16 + col0;
                ctx[((size_t)b * S_ + q) * H_ + h * HD_ + d] = f2bf_rn(Oacc[nt][reg] * rl[reg]);
            }
    }
}

// ---------------------------------------------------------------- launch
extern "C" void kernel_launch(void* const* d_in, const int* in_sizes, int n_in,
                              void* d_out, int out_size, void* d_ws, size_t ws_size,
                              hipStream_t stream) {
    const float* x     = (const float*)d_in[0];
    const int*   mask  = (const int*)d_in[1];
    const float* normw = (const float*)d_in[2];
    const float* normb = (const float*)d_in[3];
    const float* qkvw  = (const float*)d_in[4];
    const float* qkvb  = (const float*)d_in[5];
    const float* ow    = (const float*)d_in[6];
    const float* ob    = (const float*)d_in[7];
    float* out = (float*)d_out;

    char* ws = (char*)d_ws;
    unsigned short* xn_bf   = (unsigned short*)(ws);                      //  8 MB
    unsigned short* qkvwT   = (unsigned short*)(ws + (8ull  << 20));      //  6 MB
    unsigned short* owT     = (unsigned short*)(ws + (14ull << 20));      //  2 MB
    unsigned short* Qb      = (unsigned short*)(ws + (16ull << 20));      //  8 MB [bh][s][d]
    unsigned short* Kb      = (unsigned short*)(ws + (24ull << 20));      //  8 MB [bh][s][d]
    unsigned short* Vtb     = (unsigned short*)(ws + (32ull << 20));      //  8 MB [bh][d][s]
    unsigned short* ctx_bf  = (unsigned short*)(ws + (40ull << 20));      //  8 MB

    prep_k<<<T_ + 1024, 256, 0, stream>>>(x, normw, normb, xn_bf, qkvw, ow, qkvwT, owT);
    gemm_qkv_k<<<dim3(H3_ / BN, T_ / BM), 256, 0, stream>>>(xn_bf, qkvwT, qkvb, Qb, Kb, Vtb);
    attn_k<<<768, 256, 0, stream>>>(Qb, Kb, Vtb, mask, ctx_bf);
    gemm_proj_k<<<dim3(H_ / BN, T_ / BM), 256, 0, stream>>>(ctx_bf, owT, ob, out, T_, H_, H_);
}